// Round 5
// baseline (547.802 us; speedup 1.0000x reference)
//
#include <hip/hip_runtime.h>
#include <cstdint>
#include <cstddef>

#define NN 50000
#define NE 200000
#define IND 768
#define HID 256
#define OUTD 64
#define NB 196  // ceil(NN/256)

typedef __bf16 bf16;
typedef __bf16 bf16x4 __attribute__((ext_vector_type(4)));
typedef __bf16 bf16x8 __attribute__((ext_vector_type(8)));
typedef float f32x4 __attribute__((ext_vector_type(4)));

// ---------------- edge prep: last-write-wins index + dst histogram ----------------
__global__ __launch_bounds__(256) void k_edge_prep(const int* __restrict__ ei,
                                                   int* __restrict__ le, int* __restrict__ deg) {
  int e = blockIdx.x * 256 + threadIdx.x;
  if (e < NE) {
    atomicMax(&le[ei[e]], e);
    atomicAdd(&deg[ei[NE + e]], 1);
  }
}

// ---------------- CSR build ----------------
__global__ __launch_bounds__(256) void k_scan_block(const int* __restrict__ deg,
                                                    int* __restrict__ excl, int* __restrict__ bsum) {
  __shared__ int sm[256];
  int tid = threadIdx.x;
  int i = blockIdx.x * 256 + tid;
  int v = (i < NN) ? deg[i] : 0;
  sm[tid] = v;
  __syncthreads();
#pragma unroll
  for (int off = 1; off < 256; off <<= 1) {
    int t = (tid >= off) ? sm[tid - off] : 0;
    __syncthreads();
    sm[tid] += t;
    __syncthreads();
  }
  if (i < NN) excl[i] = sm[tid] - v;
  if (tid == 255) bsum[blockIdx.x] = sm[255];
}

__global__ __launch_bounds__(256) void k_scan_partials(const int* __restrict__ bsum,
                                                       int* __restrict__ bbase) {
  __shared__ int sm[256];
  int tid = threadIdx.x;
  int v = (tid < NB) ? bsum[tid] : 0;
  sm[tid] = v;
  __syncthreads();
#pragma unroll
  for (int off = 1; off < 256; off <<= 1) {
    int t = (tid >= off) ? sm[tid - off] : 0;
    __syncthreads();
    sm[tid] += t;
    __syncthreads();
  }
  bbase[tid] = sm[tid] - v;
}

// also computes tmod[i] = etype of last incident src-edge (or -1)
__global__ __launch_bounds__(256) void k_add_base(const int* __restrict__ excl,
                                                  const int* __restrict__ bbase,
                                                  const int* __restrict__ le,
                                                  const int* __restrict__ et,
                                                  int* __restrict__ rowstart, int* __restrict__ cur,
                                                  int* __restrict__ tmod) {
  int i = blockIdx.x * 256 + threadIdx.x;
  if (i < NN) {
    int rs = excl[i] + bbase[i >> 8];
    rowstart[i] = rs;
    cur[i] = rs;
    int l = le[i];
    tmod[i] = (l >= 0) ? et[l] : -1;
  }
}

__global__ __launch_bounds__(256) void k_scatter_csr(const int* __restrict__ ei,
                                                     int* __restrict__ cur, int* __restrict__ csr) {
  int e = blockIdx.x * 256 + threadIdx.x;
  if (e < NE) {
    int d = ei[NE + e];
    int pos = atomicAdd(&cur[d], 1);
    csr[pos] = ei[e];
  }
}

// ---------------- prep: W1t, W2t (bf16 transposes) + P = emb @ W1 (fp32) ----------------
__global__ __launch_bounds__(256) void k_prep(const float* __restrict__ W1,
                                              const float* __restrict__ W2,
                                              const float* __restrict__ eemb,
                                              bf16* __restrict__ W1t,
                                              bf16* __restrict__ W2t,
                                              float* __restrict__ P) {
  int b = blockIdx.x, tid = threadIdx.x;
  if (b < 768) {                       // W1 [768][256] -> W1t [256][768]
    int k = b, n = tid;
    W1t[n * 768 + k] = (bf16)W1[k * 256 + n];
  } else if (b < 768 + 64) {           // W2 [256][64] -> W2t [64][256]
    int k = (b - 768) * 4 + (tid >> 6);
    int n = tid & 63;
    W2t[n * 256 + k] = (bf16)W2[k * 64 + n];
  } else {                             // P[r][c] = sum_k emb[r][k] * W1[k][c]
    int r = b - 832, c = tid;
    float s = 0.f;
    for (int k = 0; k < 768; k++) s += eemb[r * 768 + k] * W1[k * 256 + c];
    P[r * 256 + c] = s;
  }
}

// ---------------- GEMM1: h1 = bf16(x) @ W1t^T + P[tmod], fused logits ----------------
// 128x128 tile, BK=32, waves 2x2. Double-buffered LDS (rows padded to 40 bf16),
// register prefetch of tile k+1 overlapping MFMA of tile k; fp32->bf16 once at staging.
__global__ __launch_bounds__(256) void k_gemm1(const float* __restrict__ Ax,
                                               const bf16* __restrict__ Bt,
                                               const int* __restrict__ tmod,
                                               const float* __restrict__ P,
                                               bf16* __restrict__ C,
                                               const float* __restrict__ aS,
                                               const float* __restrict__ aD,
                                               float* __restrict__ alS,
                                               float* __restrict__ alD) {
  __shared__ bf16 As[2][128 * 40];  // 2 x 10 KB
  __shared__ bf16 Bs[2][128 * 40];  // 2 x 10 KB
  const int tid = threadIdx.x, lane = tid & 63, wave = tid >> 6;
  const int wr = wave >> 1, wc = wave & 1;
  const int ln15 = lane & 15, q = lane >> 4;
  const int n0 = blockIdx.x * 128, m0 = blockIdx.y * 128;

  // A staging: 4 loads x 32 rows; thread -> row tid>>3, float-chunk (tid&7)*4
  const int ar = tid >> 3, ac = (tid & 7) * 4;
  // B staging: 2 loads x 64 rows; thread -> row tid>>2, bf16-chunk (tid&3)*8
  const int br = tid >> 2, bc = (tid & 3) * 8;

  int arow[4];
#pragma unroll
  for (int j = 0; j < 4; j++) arow[j] = min(m0 + j * 32 + ar, NN - 1);

  float4 rA[4];
  int4 rB[2];
  auto loadT = [&](int kt) {
#pragma unroll
    for (int j = 0; j < 4; j++)
      rA[j] = *(const float4*)(Ax + (size_t)arow[j] * IND + kt + ac);
#pragma unroll
    for (int j = 0; j < 2; j++)
      rB[j] = *(const int4*)(Bt + (size_t)(n0 + j * 64 + br) * IND + kt + bc);
  };
  auto storeT = [&](int p) {
#pragma unroll
    for (int j = 0; j < 4; j++) {
      bf16x4 t;
      t[0] = (bf16)rA[j].x; t[1] = (bf16)rA[j].y; t[2] = (bf16)rA[j].z; t[3] = (bf16)rA[j].w;
      *(bf16x4*)(&As[p][(j * 32 + ar) * 40 + ac]) = t;
    }
#pragma unroll
    for (int j = 0; j < 2; j++)
      *(int4*)(&Bs[p][(j * 64 + br) * 40 + bc]) = rB[j];
  };

  f32x4 acc[4][4] = {};
  loadT(0);
  storeT(0);
  int p = 0;
  for (int kt = 0; kt < IND; kt += 32) {
    __syncthreads();  // buf p staged; prev reads of buf p^1 done
    bool more = (kt + 32) < IND;
    if (more) loadT(kt + 32);  // global loads in flight across compute
    bf16x8 af[4], bfr[4];
#pragma unroll
    for (int mi = 0; mi < 4; mi++)
      af[mi] = *(const bf16x8*)(&As[p][(wr * 64 + mi * 16 + ln15) * 40 + q * 8]);
#pragma unroll
    for (int ni = 0; ni < 4; ni++)
      bfr[ni] = *(const bf16x8*)(&Bs[p][(wc * 64 + ni * 16 + ln15) * 40 + q * 8]);
#pragma unroll
    for (int mi = 0; mi < 4; mi++)
#pragma unroll
      for (int ni = 0; ni < 4; ni++)
        acc[mi][ni] = __builtin_amdgcn_mfma_f32_16x16x32_bf16(af[mi], bfr[ni], acc[mi][ni], 0, 0, 0);
    if (more) storeT(p ^ 1);  // waits vmcnt here, after MFMAs issued
    p ^= 1;
  }

  // epilogue: add P[tmod[row]], store bf16 C, emit per-head logits
  const int hd = (n0 + wc * 64) >> 6;
#pragma unroll
  for (int mi = 0; mi < 4; mi++) {
#pragma unroll
    for (int r = 0; r < 4; r++) {
      int row = m0 + wr * 64 + mi * 16 + q * 4 + r;
      bool vr = row < NN;
      int t = tmod[vr ? row : NN - 1];
      float ps = 0.f, pd = 0.f;
#pragma unroll
      for (int ni = 0; ni < 4; ni++) {
        int col = n0 + wc * 64 + ni * 16 + ln15;
        float val = acc[mi][ni][r];
        if (t >= 0) val += P[t * HID + col];
        ps += val * aS[col];
        pd += val * aD[col];
        if (vr) C[(size_t)row * HID + col] = (bf16)val;
      }
#pragma unroll
      for (int o = 1; o < 16; o <<= 1) { ps += __shfl_xor(ps, o); pd += __shfl_xor(pd, o); }
      if (ln15 == 0 && vr) { alS[row * 4 + hd] = ps; alD[row * 4 + hd] = pd; }
    }
  }
}

// ---------------- GEMM2: h2 = hln @ W2t^T, fused logits. 128x64 tile, dbuf pipeline ----------------
__global__ __launch_bounds__(256) void k_gemm2(const bf16* __restrict__ A,
                                               const bf16* __restrict__ Bt,
                                               float* __restrict__ C,
                                               const float* __restrict__ aS,
                                               const float* __restrict__ aD,
                                               float* __restrict__ alS,
                                               float* __restrict__ alD) {
  __shared__ bf16 As[2][128 * 40];  // 2 x 10 KB
  __shared__ bf16 Bs[2][64 * 40];   // 2 x 5 KB
  const int tid = threadIdx.x, lane = tid & 63, wave = tid >> 6;
  const int ln15 = lane & 15, q = lane >> 4;
  const int m0 = blockIdx.x * 128;
  const int br = tid >> 2, bc = (tid & 3) * 8;

  int arow[2];
#pragma unroll
  for (int j = 0; j < 2; j++) arow[j] = min(m0 + j * 64 + br, NN - 1);

  int4 rA[2], rB;
  auto loadT = [&](int kt) {
#pragma unroll
    for (int j = 0; j < 2; j++)
      rA[j] = *(const int4*)(A + (size_t)arow[j] * HID + kt + bc);
    rB = *(const int4*)(Bt + (size_t)br * HID + kt + bc);
  };
  auto storeT = [&](int p) {
#pragma unroll
    for (int j = 0; j < 2; j++)
      *(int4*)(&As[p][(j * 64 + br) * 40 + bc]) = rA[j];
    *(int4*)(&Bs[p][br * 40 + bc]) = rB;
  };

  f32x4 acc[2][4] = {};
  loadT(0);
  storeT(0);
  int p = 0;
  for (int kt = 0; kt < HID; kt += 32) {
    __syncthreads();
    bool more = (kt + 32) < HID;
    if (more) loadT(kt + 32);
    bf16x8 af[2], bfr[4];
#pragma unroll
    for (int mi = 0; mi < 2; mi++)
      af[mi] = *(const bf16x8*)(&As[p][(wave * 32 + mi * 16 + ln15) * 40 + q * 8]);
#pragma unroll
    for (int ni = 0; ni < 4; ni++)
      bfr[ni] = *(const bf16x8*)(&Bs[p][(ni * 16 + ln15) * 40 + q * 8]);
#pragma unroll
    for (int mi = 0; mi < 2; mi++)
#pragma unroll
      for (int ni = 0; ni < 4; ni++)
        acc[mi][ni] = __builtin_amdgcn_mfma_f32_16x16x32_bf16(af[mi], bfr[ni], acc[mi][ni], 0, 0, 0);
    if (more) storeT(p ^ 1);
    p ^= 1;
  }

#pragma unroll
  for (int mi = 0; mi < 2; mi++) {
#pragma unroll
    for (int r = 0; r < 4; r++) {
      int row = m0 + wave * 32 + mi * 16 + q * 4 + r;
      bool vr = row < NN;
      float ps = 0.f, pd = 0.f;
#pragma unroll
      for (int ni = 0; ni < 4; ni++) {
        int col = ni * 16 + ln15;
        float val = acc[mi][ni][r];
        ps += val * aS[col];
        pd += val * aD[col];
        if (vr) C[(size_t)row * OUTD + col] = val;
      }
#pragma unroll
      for (int o = 1; o < 16; o <<= 1) { ps += __shfl_xor(ps, o); pd += __shfl_xor(pd, o); }
      if (ln15 == 0 && vr) { alS[row] = ps; alD[row] = pd; }
    }
  }
}

// ---------------- fused gather-aggregate + LN + ELU, layer 1 (simple loop) ----------------
__global__ __launch_bounds__(256) void k_agg_ln1(const int* __restrict__ rowstart,
                                                 const int* __restrict__ deg,
                                                 const int* __restrict__ csr,
                                                 const bf16* __restrict__ h1,
                                                 const float* __restrict__ alS,
                                                 const float* __restrict__ alD,
                                                 const float* __restrict__ b1,
                                                 const float* __restrict__ g1,
                                                 const float* __restrict__ be1,
                                                 bf16* __restrict__ hln) {
  __shared__ float red[8];
  int n = blockIdx.x, f = threadIdx.x, hd = f >> 6;
  int start = rowstart[n], cnt = deg[n];
  float ald = alD[n * 4 + hd];
  float accv = 0.f, accw = 0.f;
  for (int j = 0; j < cnt; j++) {
    int s = csr[start + j];
    float lg = alS[s * 4 + hd] + ald;
    lg = lg >= 0.f ? lg : 0.2f * lg;
    float w = __expf(lg);  // shift-free softmax: logits bounded by construction
    accv += w * (float)h1[(size_t)s * HID + f];
    accw += w;
  }
  float v = (cnt > 0) ? accv / accw : 0.f;
  v += b1[f];
  float s = v, ss = v * v;
#pragma unroll
  for (int off = 32; off; off >>= 1) { s += __shfl_xor(s, off); ss += __shfl_xor(ss, off); }
  if ((f & 63) == 0) { red[f >> 6] = s; red[4 + (f >> 6)] = ss; }
  __syncthreads();
  float tot = red[0] + red[1] + red[2] + red[3];
  float tss = red[4] + red[5] + red[6] + red[7];
  float mu = tot * (1.f / HID);
  float var = tss * (1.f / HID) - mu * mu;
  float y = (v - mu) * rsqrtf(var + 1e-5f) * g1[f] + be1[f];
  y = y > 0.f ? y : __expf(y) - 1.f;  // ELU
  hln[(size_t)n * HID + f] = (bf16)y;
}

// ---------------- fused gather-aggregate + LN, layer 2 (4 nodes/block, simple loop) ----------------
__global__ __launch_bounds__(256) void k_agg_ln2(const int* __restrict__ rowstart,
                                                 const int* __restrict__ deg,
                                                 const int* __restrict__ csr,
                                                 const float* __restrict__ h2,
                                                 const float* __restrict__ alS,
                                                 const float* __restrict__ alD,
                                                 const float* __restrict__ b2,
                                                 const float* __restrict__ g2,
                                                 const float* __restrict__ be2,
                                                 float* __restrict__ out) {
  int n = blockIdx.x * 4 + (threadIdx.x >> 6);
  int f = threadIdx.x & 63;
  int start = rowstart[n], cnt = deg[n];
  float ald = alD[n];
  float accv = 0.f, accw = 0.f;
  for (int j = 0; j < cnt; j++) {
    int s = csr[start + j];
    float lg = alS[s] + ald;
    lg = lg >= 0.f ? lg : 0.2f * lg;
    float w = __expf(lg);
    accv += w * h2[(size_t)s * OUTD + f];
    accw += w;
  }
  float v = (cnt > 0) ? accv / accw : 0.f;
  v += b2[f];
  float s = v, ss = v * v;
#pragma unroll
  for (int off = 32; off; off >>= 1) { s += __shfl_xor(s, off); ss += __shfl_xor(ss, off); }
  float mu = s * (1.f / OUTD);
  float var = ss * (1.f / OUTD) - mu * mu;
  out[(size_t)n * OUTD + f] = (v - mu) * rsqrtf(var + 1e-5f) * g2[f] + be2[f];
}

extern "C" void kernel_launch(void* const* d_in, const int* in_sizes, int n_in,
                              void* d_out, int out_size, void* d_ws, size_t ws_size,
                              hipStream_t stream) {
  const float* x    = (const float*)d_in[0];
  const int*   ei   = (const int*)d_in[1];
  const int*   et   = (const int*)d_in[2];
  const float* eemb = (const float*)d_in[3];
  const float* W1   = (const float*)d_in[4];
  const float* as1  = (const float*)d_in[5];
  const float* ad1  = (const float*)d_in[6];
  const float* b1   = (const float*)d_in[7];
  const float* g1   = (const float*)d_in[8];
  const float* be1  = (const float*)d_in[9];
  const float* W2   = (const float*)d_in[10];
  const float* as2  = (const float*)d_in[11];
  const float* ad2  = (const float*)d_in[12];
  const float* b2   = (const float*)d_in[13];
  const float* g2   = (const float*)d_in[14];
  const float* be2  = (const float*)d_in[15];
  float* out = (float*)d_out;

  char* base = (char*)d_ws;
  size_t off = 0;
  auto alloc = [&](size_t bytes) -> void* {
    void* p = base + off;
    off = (off + bytes + 255) & ~(size_t)255;
    return p;
  };
  int*   le    = (int*)alloc((size_t)NN * 4);
  int*   deg   = (int*)alloc((size_t)NN * 4);
  int*   excl  = (int*)alloc((size_t)NN * 4);
  int*   bsum  = (int*)alloc(256 * 4);
  int*   bbase = (int*)alloc(256 * 4);
  int*   rowst = (int*)alloc((size_t)NN * 4);
  int*   cur   = (int*)alloc((size_t)NN * 4);
  int*   tmod  = (int*)alloc((size_t)NN * 4);
  int*   csr   = (int*)alloc((size_t)NE * 4);
  bf16*  h1    = (bf16*)alloc((size_t)NN * HID * 2);
  float* alS1  = (float*)alloc((size_t)NN * 4 * 4);
  float* alD1  = (float*)alloc((size_t)NN * 4 * 4);
  bf16*  hln   = (bf16*)alloc((size_t)NN * HID * 2);
  float* h2    = (float*)alloc((size_t)NN * OUTD * 4);
  float* alS2  = (float*)alloc((size_t)NN * 4);
  float* alD2  = (float*)alloc((size_t)NN * 4);
  bf16*  W1t   = (bf16*)alloc((size_t)HID * IND * 2);
  bf16*  W2t   = (bf16*)alloc((size_t)OUTD * HID * 2);
  float* P     = (float*)alloc(6 * HID * 4);

  hipMemsetAsync(le, 0xFF, (size_t)NN * 4, stream);  // -1
  hipMemsetAsync(deg, 0, (size_t)NN * 4, stream);

  // CSR + last-edge prep
  k_edge_prep<<<(NE + 255) / 256, 256, 0, stream>>>(ei, le, deg);
  k_scan_block<<<NB, 256, 0, stream>>>(deg, excl, bsum);
  k_scan_partials<<<1, 256, 0, stream>>>(bsum, bbase);
  k_add_base<<<NB, 256, 0, stream>>>(excl, bbase, le, et, rowst, cur, tmod);
  k_scatter_csr<<<(NE + 255) / 256, 256, 0, stream>>>(ei, cur, csr);

  // weights + P
  k_prep<<<838, 256, 0, stream>>>(W1, W2, eemb, W1t, W2t, P);

  // layer 1
  k_gemm1<<<dim3(2, (NN + 127) / 128), 256, 0, stream>>>(x, W1t, tmod, P, h1, as1, ad1, alS1, alD1);
  k_agg_ln1<<<NN, 256, 0, stream>>>(rowst, deg, csr, h1, alS1, alD1, b1, g1, be1, hln);

  // layer 2
  k_gemm2<<<(NN + 127) / 128, 256, 0, stream>>>(hln, W2t, h2, as2, ad2, alS2, alD2);
  k_agg_ln2<<<NN / 4, 256, 0, stream>>>(rowst, deg, csr, h2, alS2, alD2, b2, g2, be2, out);
}

// Round 6
// 537.594 us; speedup vs baseline: 1.0190x; 1.0190x over previous
//
#include <hip/hip_runtime.h>
#include <cstdint>
#include <cstddef>

#define NN 50000
#define NE 200000
#define IND 768
#define HID 256
#define OUTD 64
#define NB 196  // ceil(NN/256)

typedef __bf16 bf16;
typedef __bf16 bf16x4 __attribute__((ext_vector_type(4)));
typedef __bf16 bf16x8 __attribute__((ext_vector_type(8)));
typedef float f32x4 __attribute__((ext_vector_type(4)));

// ---------------- init: le=-1, deg=0 (one kernel instead of two memsets) ----------------
__global__ __launch_bounds__(256) void k_init(int* __restrict__ le, int* __restrict__ deg) {
  int i = blockIdx.x * 256 + threadIdx.x;
  if (i < NN) { le[i] = -1; deg[i] = 0; }
}

// ---------------- edge prep: last-write-wins index + dst histogram ----------------
__global__ __launch_bounds__(256) void k_edge_prep(const int* __restrict__ ei,
                                                   int* __restrict__ le, int* __restrict__ deg) {
  int e = blockIdx.x * 256 + threadIdx.x;
  if (e < NE) {
    atomicMax(&le[ei[e]], e);
    atomicAdd(&deg[ei[NE + e]], 1);
  }
}

// ---------------- CSR build ----------------
__global__ __launch_bounds__(256) void k_scan_block(const int* __restrict__ deg,
                                                    int* __restrict__ excl, int* __restrict__ bsum) {
  __shared__ int sm[256];
  int tid = threadIdx.x;
  int i = blockIdx.x * 256 + tid;
  int v = (i < NN) ? deg[i] : 0;
  sm[tid] = v;
  __syncthreads();
#pragma unroll
  for (int off = 1; off < 256; off <<= 1) {
    int t = (tid >= off) ? sm[tid - off] : 0;
    __syncthreads();
    sm[tid] += t;
    __syncthreads();
  }
  if (i < NN) excl[i] = sm[tid] - v;
  if (tid == 255) bsum[blockIdx.x] = sm[255];
}

__global__ __launch_bounds__(256) void k_scan_partials(const int* __restrict__ bsum,
                                                       int* __restrict__ bbase) {
  __shared__ int sm[256];
  int tid = threadIdx.x;
  int v = (tid < NB) ? bsum[tid] : 0;
  sm[tid] = v;
  __syncthreads();
#pragma unroll
  for (int off = 1; off < 256; off <<= 1) {
    int t = (tid >= off) ? sm[tid - off] : 0;
    __syncthreads();
    sm[tid] += t;
    __syncthreads();
  }
  bbase[tid] = sm[tid] - v;
}

__global__ __launch_bounds__(256) void k_add_base(const int* __restrict__ excl,
                                                  const int* __restrict__ bbase,
                                                  const int* __restrict__ le,
                                                  const int* __restrict__ et,
                                                  int* __restrict__ rowstart, int* __restrict__ cur,
                                                  int* __restrict__ tmod) {
  int i = blockIdx.x * 256 + threadIdx.x;
  if (i < NN) {
    int rs = excl[i] + bbase[i >> 8];
    rowstart[i] = rs;
    cur[i] = rs;
    int l = le[i];
    tmod[i] = (l >= 0) ? et[l] : -1;
  }
}

__global__ __launch_bounds__(256) void k_scatter_csr(const int* __restrict__ ei,
                                                     int* __restrict__ cur, int* __restrict__ csr) {
  int e = blockIdx.x * 256 + threadIdx.x;
  if (e < NE) {
    int d = ei[NE + e];
    int pos = atomicAdd(&cur[d], 1);
    csr[pos] = ei[e];
  }
}

// ---------------- prep: W1t, W2t (bf16 transposes) + P = emb @ W1 (fp32) ----------------
__global__ __launch_bounds__(256) void k_prep(const float* __restrict__ W1,
                                              const float* __restrict__ W2,
                                              const float* __restrict__ eemb,
                                              bf16* __restrict__ W1t,
                                              bf16* __restrict__ W2t,
                                              float* __restrict__ P) {
  int b = blockIdx.x, tid = threadIdx.x;
  if (b < 768) {                       // W1 [768][256] -> W1t [256][768]
    int k = b, n = tid;
    W1t[n * 768 + k] = (bf16)W1[k * 256 + n];
  } else if (b < 768 + 64) {           // W2 [256][64] -> W2t [64][256]
    int k = (b - 768) * 4 + (tid >> 6);
    int n = tid & 63;
    W2t[n * 256 + k] = (bf16)W2[k * 64 + n];
  } else {                             // P[r][c] = sum_k emb[r][k] * W1[k][c]
    int r = b - 832, c = tid;
    float s = 0.f;
    for (int k = 0; k < 768; k++) s += eemb[r * 768 + k] * W1[k * 256 + c];
    P[r * 256 + c] = s;
  }
}

// ---------------- GEMM1: h1 = bf16(x) @ W1t^T + P[tmod], fused logits ----------------
// Single-wave workgroups, 64x64 wave-tile, NO LDS, NO barriers. Fragments load
// straight from global into registers; two-phase K-loop (depth-1 prefetch) lets
// the compiler emit fine-grained vmcnt. A re-reads (4 N-tiles) served by L3
// (x = 153.6 MB < 256 MB); B (384 KB) L2-resident.
__global__ __launch_bounds__(64) void k_gemm1(const float* __restrict__ Ax,
                                              const bf16* __restrict__ Bt,
                                              const int* __restrict__ tmod,
                                              const float* __restrict__ P,
                                              bf16* __restrict__ C,
                                              const float* __restrict__ aS,
                                              const float* __restrict__ aD,
                                              float* __restrict__ alS,
                                              float* __restrict__ alD) {
  const int lane = threadIdx.x;
  const int ln15 = lane & 15, q = lane >> 4;
  const int n0 = blockIdx.x * 64, m0 = blockIdx.y * 64;
  const int hd = n0 >> 6;

  size_t aoff[4], boff[4];
#pragma unroll
  for (int mi = 0; mi < 4; mi++)
    aoff[mi] = (size_t)min(m0 + mi * 16 + ln15, NN - 1) * IND + q * 8;
#pragma unroll
  for (int ni = 0; ni < 4; ni++)
    boff[ni] = (size_t)(n0 + ni * 16 + ln15) * IND + q * 8;

  float4 xa0[4], xa1[4], ya0[4], ya1[4];
  bf16x8 xb[4], yb[4];

#define LOAD_SET(A0, A1, B, KT)                                        \
  {                                                                    \
    _Pragma("unroll") for (int i = 0; i < 4; i++) {                    \
      A0[i] = *(const float4*)(Ax + aoff[i] + (KT));                   \
      A1[i] = *(const float4*)(Ax + aoff[i] + (KT) + 4);               \
    }                                                                  \
    _Pragma("unroll") for (int i = 0; i < 4; i++)                      \
        B[i] = *(const bf16x8*)(Bt + boff[i] + (KT));                  \
  }

#define COMPUTE_SET(A0, A1, B)                                         \
  {                                                                    \
    bf16x8 af[4];                                                      \
    _Pragma("unroll") for (int i = 0; i < 4; i++) {                    \
      bf16x8 t;                                                        \
      t[0] = (bf16)A0[i].x; t[1] = (bf16)A0[i].y;                      \
      t[2] = (bf16)A0[i].z; t[3] = (bf16)A0[i].w;                      \
      t[4] = (bf16)A1[i].x; t[5] = (bf16)A1[i].y;                      \
      t[6] = (bf16)A1[i].z; t[7] = (bf16)A1[i].w;                      \
      af[i] = t;                                                       \
    }                                                                  \
    _Pragma("unroll") for (int mi = 0; mi < 4; mi++)                   \
        _Pragma("unroll") for (int ni = 0; ni < 4; ni++)               \
            acc[mi][ni] = __builtin_amdgcn_mfma_f32_16x16x32_bf16(     \
                af[mi], B[ni], acc[mi][ni], 0, 0, 0);                  \
  }

  f32x4 acc[4][4] = {};
  LOAD_SET(xa0, xa1, xb, 0)
  for (int kt = 0; kt < IND; kt += 64) {
    LOAD_SET(ya0, ya1, yb, kt + 32)
    COMPUTE_SET(xa0, xa1, xb)
    if (kt + 64 < IND) LOAD_SET(xa0, xa1, xb, kt + 64)
    COMPUTE_SET(ya0, ya1, yb)
  }
#undef LOAD_SET
#undef COMPUTE_SET

  // epilogue: add P[tmod[row]], store bf16 C, emit per-head logits
#pragma unroll
  for (int mi = 0; mi < 4; mi++) {
#pragma unroll
    for (int r = 0; r < 4; r++) {
      int row = m0 + mi * 16 + q * 4 + r;
      bool vr = row < NN;
      int t = tmod[vr ? row : NN - 1];
      float ps = 0.f, pd = 0.f;
#pragma unroll
      for (int ni = 0; ni < 4; ni++) {
        int col = n0 + ni * 16 + ln15;
        float val = acc[mi][ni][r];
        if (t >= 0) val += P[t * HID + col];
        ps += val * aS[col];
        pd += val * aD[col];
        if (vr) C[(size_t)row * HID + col] = (bf16)val;
      }
#pragma unroll
      for (int o = 1; o < 16; o <<= 1) { ps += __shfl_xor(ps, o); pd += __shfl_xor(pd, o); }
      if (ln15 == 0 && vr) { alS[row * 4 + hd] = ps; alD[row * 4 + hd] = pd; }
    }
  }
}

// ---------------- GEMM2: h2 = hln @ W2t^T, fused logits. Single-wave 32x64 tiles ----------------
__global__ __launch_bounds__(64) void k_gemm2(const bf16* __restrict__ A,
                                              const bf16* __restrict__ Bt,
                                              float* __restrict__ C,
                                              const float* __restrict__ aS,
                                              const float* __restrict__ aD,
                                              float* __restrict__ alS,
                                              float* __restrict__ alD) {
  const int lane = threadIdx.x;
  const int ln15 = lane & 15, q = lane >> 4;
  const int m0 = blockIdx.x * 32;

  size_t aoff[2], boff[4];
#pragma unroll
  for (int mi = 0; mi < 2; mi++)
    aoff[mi] = (size_t)min(m0 + mi * 16 + ln15, NN - 1) * HID + q * 8;
#pragma unroll
  for (int ni = 0; ni < 4; ni++)
    boff[ni] = (size_t)(ni * 16 + ln15) * HID + q * 8;

  bf16x8 xa[2], xb[4], ya[2], yb[4];

#define LOAD_SET2(AA, BB, KT)                                          \
  {                                                                    \
    _Pragma("unroll") for (int i = 0; i < 2; i++)                      \
        AA[i] = *(const bf16x8*)(A + aoff[i] + (KT));                  \
    _Pragma("unroll") for (int i = 0; i < 4; i++)                      \
        BB[i] = *(const bf16x8*)(Bt + boff[i] + (KT));                 \
  }

#define COMPUTE_SET2(AA, BB)                                           \
  {                                                                    \
    _Pragma("unroll") for (int mi = 0; mi < 2; mi++)                   \
        _Pragma("unroll") for (int ni = 0; ni < 4; ni++)               \
            acc[mi][ni] = __builtin_amdgcn_mfma_f32_16x16x32_bf16(     \
                AA[mi], BB[ni], acc[mi][ni], 0, 0, 0);                 \
  }

  f32x4 acc[2][4] = {};
  LOAD_SET2(xa, xb, 0)
  for (int kt = 0; kt < HID; kt += 64) {
    LOAD_SET2(ya, yb, kt + 32)
    COMPUTE_SET2(xa, xb)
    if (kt + 64 < HID) LOAD_SET2(xa, xb, kt + 64)
    COMPUTE_SET2(ya, yb)
  }
#undef LOAD_SET2
#undef COMPUTE_SET2

#pragma unroll
  for (int mi = 0; mi < 2; mi++) {
#pragma unroll
    for (int r = 0; r < 4; r++) {
      int row = m0 + mi * 16 + q * 4 + r;
      bool vr = row < NN;
      float ps = 0.f, pd = 0.f;
#pragma unroll
      for (int ni = 0; ni < 4; ni++) {
        int col = ni * 16 + ln15;
        float val = acc[mi][ni][r];
        ps += val * aS[col];
        pd += val * aD[col];
        if (vr) C[(size_t)row * OUTD + col] = val;
      }
#pragma unroll
      for (int o = 1; o < 16; o <<= 1) { ps += __shfl_xor(ps, o); pd += __shfl_xor(pd, o); }
      if (ln15 == 0 && vr) { alS[row] = ps; alD[row] = pd; }
    }
  }
}

// ---------------- fused gather-aggregate + LN + ELU, layer 1 ----------------
// One wave per node; lane owns 4 contiguous cols (bf16x4 loads, 8B/lane).
__global__ __launch_bounds__(256) void k_agg_ln1(const int* __restrict__ rowstart,
                                                 const int* __restrict__ deg,
                                                 const int* __restrict__ csr,
                                                 const bf16* __restrict__ h1,
                                                 const float* __restrict__ alS,
                                                 const float* __restrict__ alD,
                                                 const float* __restrict__ b1,
                                                 const float* __restrict__ g1,
                                                 const float* __restrict__ be1,
                                                 bf16* __restrict__ hln) {
  const int wave = threadIdx.x >> 6, lane = threadIdx.x & 63;
  const int n = blockIdx.x * 4 + wave;       // NN % 4 == 0
  const int hd = lane >> 4;                  // lane's 4-col slice lies in head hd
  const int c0 = lane * 4;
  int start = rowstart[n], cnt = deg[n];
  float ald = alD[n * 4 + hd];
  float av0 = 0.f, av1 = 0.f, av2 = 0.f, av3 = 0.f, accw = 0.f;
  for (int j = 0; j < cnt; j++) {
    int s = csr[start + j];
    float lg = alS[s * 4 + hd] + ald;
    lg = lg >= 0.f ? lg : 0.2f * lg;
    float w = __expf(lg);  // shift-free softmax: logits bounded by construction
    bf16x4 hv = *(const bf16x4*)(h1 + (size_t)s * HID + c0);
    av0 += w * (float)hv[0]; av1 += w * (float)hv[1];
    av2 += w * (float)hv[2]; av3 += w * (float)hv[3];
    accw += w;
  }
  float inv = (cnt > 0) ? 1.f / accw : 0.f;
  float4 bv = *(const float4*)(b1 + c0);
  float v0 = av0 * inv + bv.x, v1 = av1 * inv + bv.y;
  float v2 = av2 * inv + bv.z, v3 = av3 * inv + bv.w;
  float s = v0 + v1 + v2 + v3;
  float ss = v0 * v0 + v1 * v1 + v2 * v2 + v3 * v3;
#pragma unroll
  for (int off = 32; off; off >>= 1) { s += __shfl_xor(s, off); ss += __shfl_xor(ss, off); }
  float mu = s * (1.f / HID);
  float var = ss * (1.f / HID) - mu * mu;
  float rstd = rsqrtf(var + 1e-5f);
  float4 gv = *(const float4*)(g1 + c0);
  float4 ev = *(const float4*)(be1 + c0);
  float y0 = (v0 - mu) * rstd * gv.x + ev.x;
  float y1 = (v1 - mu) * rstd * gv.y + ev.y;
  float y2 = (v2 - mu) * rstd * gv.z + ev.z;
  float y3 = (v3 - mu) * rstd * gv.w + ev.w;
  y0 = y0 > 0.f ? y0 : __expf(y0) - 1.f;
  y1 = y1 > 0.f ? y1 : __expf(y1) - 1.f;
  y2 = y2 > 0.f ? y2 : __expf(y2) - 1.f;
  y3 = y3 > 0.f ? y3 : __expf(y3) - 1.f;
  bf16x4 o; o[0] = (bf16)y0; o[1] = (bf16)y1; o[2] = (bf16)y2; o[3] = (bf16)y3;
  *(bf16x4*)(hln + (size_t)n * HID + c0) = o;
}

// ---------------- fused gather-aggregate + LN, layer 2 (4 nodes/block) ----------------
__global__ __launch_bounds__(256) void k_agg_ln2(const int* __restrict__ rowstart,
                                                 const int* __restrict__ deg,
                                                 const int* __restrict__ csr,
                                                 const float* __restrict__ h2,
                                                 const float* __restrict__ alS,
                                                 const float* __restrict__ alD,
                                                 const float* __restrict__ b2,
                                                 const float* __restrict__ g2,
                                                 const float* __restrict__ be2,
                                                 float* __restrict__ out) {
  int n = blockIdx.x * 4 + (threadIdx.x >> 6);
  int f = threadIdx.x & 63;
  int start = rowstart[n], cnt = deg[n];
  float ald = alD[n];
  float accv = 0.f, accw = 0.f;
  for (int j = 0; j < cnt; j++) {
    int s = csr[start + j];
    float lg = alS[s] + ald;
    lg = lg >= 0.f ? lg : 0.2f * lg;
    float w = __expf(lg);
    accv += w * h2[(size_t)s * OUTD + f];
    accw += w;
  }
  float v = (cnt > 0) ? accv / accw : 0.f;
  v += b2[f];
  float s = v, ss = v * v;
#pragma unroll
  for (int off = 32; off; off >>= 1) { s += __shfl_xor(s, off); ss += __shfl_xor(ss, off); }
  float mu = s * (1.f / OUTD);
  float var = ss * (1.f / OUTD) - mu * mu;
  out[(size_t)n * OUTD + f] = (v - mu) * rsqrtf(var + 1e-5f) * g2[f] + be2[f];
}

extern "C" void kernel_launch(void* const* d_in, const int* in_sizes, int n_in,
                              void* d_out, int out_size, void* d_ws, size_t ws_size,
                              hipStream_t stream) {
  const float* x    = (const float*)d_in[0];
  const int*   ei   = (const int*)d_in[1];
  const int*   et   = (const int*)d_in[2];
  const float* eemb = (const float*)d_in[3];
  const float* W1   = (const float*)d_in[4];
  const float* as1  = (const float*)d_in[5];
  const float* ad1  = (const float*)d_in[6];
  const float* b1   = (const float*)d_in[7];
  const float* g1   = (const float*)d_in[8];
  const float* be1  = (const float*)d_in[9];
  const float* W2   = (const float*)d_in[10];
  const float* as2  = (const float*)d_in[11];
  const float* ad2  = (const float*)d_in[12];
  const float* b2   = (const float*)d_in[13];
  const float* g2   = (const float*)d_in[14];
  const float* be2  = (const float*)d_in[15];
  float* out = (float*)d_out;

  char* base = (char*)d_ws;
  size_t off = 0;
  auto alloc = [&](size_t bytes) -> void* {
    void* p = base + off;
    off = (off + bytes + 255) & ~(size_t)255;
    return p;
  };
  int*   le    = (int*)alloc((size_t)NN * 4);
  int*   deg   = (int*)alloc((size_t)NN * 4);
  int*   excl  = (int*)alloc((size_t)NN * 4);
  int*   bsum  = (int*)alloc(256 * 4);
  int*   bbase = (int*)alloc(256 * 4);
  int*   rowst = (int*)alloc((size_t)NN * 4);
  int*   cur   = (int*)alloc((size_t)NN * 4);
  int*   tmod  = (int*)alloc((size_t)NN * 4);
  int*   csr   = (int*)alloc((size_t)NE * 4);
  bf16*  h1    = (bf16*)alloc((size_t)NN * HID * 2);
  float* alS1  = (float*)alloc((size_t)NN * 4 * 4);
  float* alD1  = (float*)alloc((size_t)NN * 4 * 4);
  bf16*  hln   = (bf16*)alloc((size_t)NN * HID * 2);
  float* h2    = (float*)alloc((size_t)NN * OUTD * 4);
  float* alS2  = (float*)alloc((size_t)NN * 4);
  float* alD2  = (float*)alloc((size_t)NN * 4);
  bf16*  W1t   = (bf16*)alloc((size_t)HID * IND * 2);
  bf16*  W2t   = (bf16*)alloc((size_t)OUTD * HID * 2);
  float* P     = (float*)alloc(6 * HID * 4);

  // CSR + last-edge prep
  k_init<<<NB, 256, 0, stream>>>(le, deg);
  k_edge_prep<<<(NE + 255) / 256, 256, 0, stream>>>(ei, le, deg);
  k_scan_block<<<NB, 256, 0, stream>>>(deg, excl, bsum);
  k_scan_partials<<<1, 256, 0, stream>>>(bsum, bbase);
  k_add_base<<<NB, 256, 0, stream>>>(excl, bbase, le, et, rowst, cur, tmod);
  k_scatter_csr<<<(NE + 255) / 256, 256, 0, stream>>>(ei, cur, csr);

  // weights + P
  k_prep<<<838, 256, 0, stream>>>(W1, W2, eemb, W1t, W2t, P);

  // layer 1
  k_gemm1<<<dim3(4, (NN + 63) / 64), 64, 0, stream>>>(x, W1t, tmod, P, h1, as1, ad1, alS1, alD1);
  k_agg_ln1<<<NN / 4, 256, 0, stream>>>(rowst, deg, csr, h1, alS1, alD1, b1, g1, be1, hln);

  // layer 2
  k_gemm2<<<(NN + 31) / 32, 64, 0, stream>>>(hln, W2t, h2, as2, ad2, alS2, alD2);
  k_agg_ln2<<<NN / 4, 256, 0, stream>>>(rowst, deg, csr, h2, alS2, alD2, b2, g2, be2, out);
}